// Round 2
// baseline (263.826 us; speedup 1.0000x reference)
//
#include <hip/hip_runtime.h>
#include <hip/hip_bf16.h>

#define HSEQ_ELEMS 16777216   // 512*32*1024
#define NH 1024
#define NBATCH 32
#define NSEQ 512

typedef __attribute__((ext_vector_type(8))) short bf16x8;
typedef __attribute__((ext_vector_type(4))) float f32x4;

__device__ __forceinline__ unsigned short f2bf(float f) {
  unsigned u = __builtin_bit_cast(unsigned, f);
  u += 0x7fffu + ((u >> 16) & 1u);
  return (unsigned short)(u >> 16);
}

__global__ __launch_bounds__(256) void cvt_kernel(const float* __restrict__ src,
                                                  unsigned short* __restrict__ dst,
                                                  int n) {
  int i = (blockIdx.x * 256 + threadIdx.x) * 4;
  int stride = gridDim.x * 256 * 4;
  for (; i < n; i += stride) {
    float4 v = *reinterpret_cast<const float4*>(src + i);
    ushort4 o;
    o.x = f2bf(v.x); o.y = f2bf(v.y); o.z = f2bf(v.z); o.w = f2bf(v.w);
    *reinterpret_cast<ushort4*>(dst + i) = o;
  }
}

// hz[g][b][h] = sum_k h0[b,k]*w_h[g][h,k] + b_i[g][h] + b_h[g][h]
__global__ __launch_bounds__(256) void hz_kernel(
    const float* __restrict__ h0,
    const float* __restrict__ wh_i, const float* __restrict__ wh_f,
    const float* __restrict__ wh_o, const float* __restrict__ wh_g,
    const float* __restrict__ bi_i, const float* __restrict__ bh_i,
    const float* __restrict__ bi_f, const float* __restrict__ bh_f,
    const float* __restrict__ bi_o, const float* __restrict__ bh_o,
    const float* __restrict__ bi_g, const float* __restrict__ bh_g,
    float* __restrict__ hz) {
  __shared__ float ws[8 * 1024];
  int g = blockIdx.x >> 7;
  int hb = blockIdx.x & 127;
  const float* wh = (g == 0) ? wh_i : (g == 1) ? wh_f : (g == 2) ? wh_o : wh_g;
  const float* bi = (g == 0) ? bi_i : (g == 1) ? bi_f : (g == 2) ? bi_o : bi_g;
  const float* bh = (g == 0) ? bh_i : (g == 1) ? bh_f : (g == 2) ? bh_o : bh_g;
  int tid = threadIdx.x;
  const float4* wsrc = reinterpret_cast<const float4*>(wh + hb * 8 * 1024);
  float4* wdst = reinterpret_cast<float4*>(ws);
  for (int i = tid; i < 2048; i += 256) wdst[i] = wsrc[i];
  __syncthreads();
  int b = tid & 31;
  int hh = tid >> 5;
  const float4* hv = reinterpret_cast<const float4*>(h0 + b * NH);
  const float4* wv = reinterpret_cast<const float4*>(ws + hh * NH);
  float acc = 0.f;
  for (int k = 0; k < 256; ++k) {
    float4 a = hv[k], w4 = wv[k];
    acc += a.x * w4.x + a.y * w4.y + a.z * w4.z + a.w * w4.w;
  }
  int h = hb * 8 + hh;
  hz[g * (NBATCH * NH) + b * NH + h] = acc + bi[h] + bh[h];
}

__device__ __forceinline__ void load_lds16(const void* gsrc, void* lds) {
  __builtin_amdgcn_global_load_lds(
      (const __attribute__((address_space(1))) unsigned int*)gsrc,
      (__attribute__((address_space(3))) unsigned int*)lds, 16, 0, 0);
}

// Block tile: M=128, effN=128 (4 gates x 32 h). 4 waves, each wave: M-sub 32, all effN.
__global__ __launch_bounds__(256, 2) void lstm_gemm(
    const unsigned short* __restrict__ xb,   // [16384][1024] bf16
    const unsigned short* __restrict__ wb,   // [4][1024][1024] bf16 (gates i,f,o,g)
    const float* __restrict__ hz,            // [4][32][1024] f32
    const float* __restrict__ c0,            // [32][1024] f32
    float* __restrict__ out) {               // f32 outputs!
  __shared__ unsigned short As[128 * 32];
  __shared__ unsigned short Bs[128 * 32];
  const int bid = blockIdx.x;
  const int ht = bid & 31;   // h-tile (32 h each)
  const int mt = bid >> 5;   // m-tile (128 m each)
  const int tid = threadIdx.x;
  const int lane = tid & 63;
  const int w = tid >> 6;

  const int srow = lane >> 2;        // row within 16-row chunk
  const int skol = (lane & 3) * 8;   // k element offset

  f32x4 acc[2][8];
  const f32x4 fzero = {0.f, 0.f, 0.f, 0.f};
#pragma unroll
  for (int i = 0; i < 2; ++i)
#pragma unroll
    for (int j = 0; j < 8; ++j) acc[i][j] = fzero;

  const int mBase = mt * 128;
  const int hBase = ht * 32;

  for (int kt = 0; kt < 32; ++kt) {
    const int k0 = kt * 32;
    // stage A: 8 chunks of 1KB, 2 per wave
#pragma unroll
    for (int j = 0; j < 2; ++j) {
      int c = w + j * 4;
      int row = c * 16 + srow;
      load_lds16(xb + (size_t)(mBase + row) * 1024 + k0 + skol, As + c * 512);
    }
    // stage B (effN rows: n = gate*32 + hh)
#pragma unroll
    for (int j = 0; j < 2; ++j) {
      int c = w + j * 4;
      int n = c * 16 + srow;
      int gate = n >> 5, hh = n & 31;
      load_lds16(wb + (size_t)gate * (1024 * 1024) + (size_t)(hBase + hh) * 1024 + k0 + skol,
                 Bs + c * 512);
    }
    __syncthreads();

    bf16x8 af[2];
#pragma unroll
    for (int mi = 0; mi < 2; ++mi) {
      int row = w * 32 + mi * 16 + (lane & 15);
      af[mi] = *reinterpret_cast<const bf16x8*>(As + row * 32 + (lane >> 4) * 8);
    }
#pragma unroll
    for (int nf = 0; nf < 8; ++nf) {
      int n = nf * 16 + (lane & 15);
      bf16x8 bfb = *reinterpret_cast<const bf16x8*>(Bs + n * 32 + (lane >> 4) * 8);
      acc[0][nf] = __builtin_amdgcn_mfma_f32_16x16x32_bf16(af[0], bfb, acc[0][nf], 0, 0, 0);
      acc[1][nf] = __builtin_amdgcn_mfma_f32_16x16x32_bf16(af[1], bfb, acc[1][nf], 0, 0, 0);
    }
    __syncthreads();
  }

  // epilogue: combine gates, activations, write f32
  const int b = mBase >> 9;  // batch index, uniform per block (128 | 512)
#pragma unroll
  for (int mi = 0; mi < 2; ++mi) {
#pragma unroll
    for (int n16 = 0; n16 < 2; ++n16) {
      int h = hBase + n16 * 16 + (lane & 15);
      float hz_i = hz[0 * 32768 + b * NH + h];
      float hz_f = hz[1 * 32768 + b * NH + h];
      float hz_o = hz[2 * 32768 + b * NH + h];
      float hz_g = hz[3 * 32768 + b * NH + h];
      float c0v = c0[b * NH + h];
#pragma unroll
      for (int r = 0; r < 4; ++r) {
        int row = w * 32 + mi * 16 + (lane >> 4) * 4 + r;
        int m = mBase + row;
        int t = m & 511;
        float zi = acc[mi][0 + n16][r] + hz_i;
        float zf = acc[mi][2 + n16][r] + hz_f;
        float zo = acc[mi][4 + n16][r] + hz_o;
        float zg = acc[mi][6 + n16][r] + hz_g;
        float iv = 1.f / (1.f + __expf(-zi));
        float fv = 1.f / (1.f + __expf(-zf));
        float ov = 1.f / (1.f + __expf(-zo));
        float gv = tanhf(zg);
        float cv = fv * c0v + iv * gv;
        float hval = ov * tanhf(cv);
        out[((size_t)t * 32 + b) * 1024 + h] = hval;
        if (t == 511) {
          out[HSEQ_ELEMS + b * NH + h] = hval;
          out[HSEQ_ELEMS + 32768 + b * NH + h] = cv;
        }
      }
    }
  }
}

extern "C" void kernel_launch(void* const* d_in, const int* in_sizes, int n_in,
                              void* d_out, int out_size, void* d_ws, size_t ws_size,
                              hipStream_t stream) {
  const float* x    = (const float*)d_in[0];
  const float* h0   = (const float*)d_in[1];
  const float* c0   = (const float*)d_in[2];
  const float* w_ii = (const float*)d_in[3];
  const float* w_hi = (const float*)d_in[5];
  const float* b_ii = (const float*)d_in[4];
  const float* b_hi = (const float*)d_in[6];
  const float* w_if = (const float*)d_in[7];
  const float* b_if = (const float*)d_in[8];
  const float* w_hf = (const float*)d_in[9];
  const float* b_hf = (const float*)d_in[10];
  const float* w_io = (const float*)d_in[11];
  const float* b_io = (const float*)d_in[12];
  const float* w_ho = (const float*)d_in[13];
  const float* b_ho = (const float*)d_in[14];
  const float* w_ig = (const float*)d_in[15];
  const float* b_ig = (const float*)d_in[16];
  const float* w_hg = (const float*)d_in[17];
  const float* b_hg = (const float*)d_in[18];

  unsigned short* xb = (unsigned short*)d_ws;          // 16777216 bf16
  unsigned short* wb = xb + 16777216;                  // 4*1048576 bf16
  float* hz = (float*)(wb + 4 * 1048576);              // 4*32*1024 f32
  float* out = (float*)d_out;

  hipLaunchKernelGGL(cvt_kernel, dim3(2048), dim3(256), 0, stream, x, xb, 16777216);
  hipLaunchKernelGGL(cvt_kernel, dim3(256), dim3(256), 0, stream, w_ii, wb + 0 * 1048576, 1048576);
  hipLaunchKernelGGL(cvt_kernel, dim3(256), dim3(256), 0, stream, w_if, wb + 1 * 1048576, 1048576);
  hipLaunchKernelGGL(cvt_kernel, dim3(256), dim3(256), 0, stream, w_io, wb + 2 * 1048576, 1048576);
  hipLaunchKernelGGL(cvt_kernel, dim3(256), dim3(256), 0, stream, w_ig, wb + 3 * 1048576, 1048576);
  hipLaunchKernelGGL(hz_kernel, dim3(512), dim3(256), 0, stream, h0,
                     w_hi, w_hf, w_ho, w_hg,
                     b_ii, b_hi, b_if, b_hf, b_io, b_ho, b_ig, b_hg, hz);
  hipLaunchKernelGGL(lstm_gemm, dim3(4096), dim3(256), 0, stream, xb, wb, hz, c0, out);
}

// Round 3
// 257.378 us; speedup vs baseline: 1.0251x; 1.0251x over previous
//
#include <hip/hip_runtime.h>
#include <hip/hip_bf16.h>

#define HSEQ 16777216   // 512*32*1024
#define NH 1024

typedef __attribute__((ext_vector_type(8))) short bf16x8;
typedef __attribute__((ext_vector_type(4))) float f32x4;

__device__ __forceinline__ unsigned short f2bf(float f) {
  unsigned u = __builtin_bit_cast(unsigned, f);
  u += 0x7fffu + ((u >> 16) & 1u);
  return (unsigned short)(u >> 16);
}

// Fused fp32->bf16 conversion: x (blocks 0-2047) + 4 gate weights (blocks 2048-3071).
__global__ __launch_bounds__(256) void cvt_all(
    const float* __restrict__ x,
    const float* __restrict__ wi, const float* __restrict__ wf,
    const float* __restrict__ wo, const float* __restrict__ wg,
    unsigned short* __restrict__ xb, unsigned short* __restrict__ wb) {
  int bid = blockIdx.x;
  const float* src; unsigned short* dst; int base, iters;
  if (bid < 2048) {
    src = x; dst = xb; base = bid * 8192; iters = 8;
  } else {
    int g = bid - 2048; int ws = g >> 8; int blk = g & 255;
    src = (ws == 0) ? wi : (ws == 1) ? wf : (ws == 2) ? wo : wg;
    dst = wb + ws * 1048576; base = blk * 4096; iters = 4;
  }
  int t = threadIdx.x;
  for (int i = 0; i < iters; ++i) {
    int idx = base + i * 1024 + t * 4;
    float4 v = *reinterpret_cast<const float4*>(src + idx);
    ushort4 o;
    o.x = f2bf(v.x); o.y = f2bf(v.y); o.z = f2bf(v.z); o.w = f2bf(v.w);
    *reinterpret_cast<ushort4*>(dst + idx) = o;
  }
}

// hz[g][b][h] = h0[b,:]·w_h[g][h,:] + b_i[g][h] + b_h[g][h]
__global__ __launch_bounds__(256) void hz_kernel(
    const float* __restrict__ h0,
    const float* __restrict__ wh_i, const float* __restrict__ wh_f,
    const float* __restrict__ wh_o, const float* __restrict__ wh_g,
    const float* __restrict__ bi_i, const float* __restrict__ bh_i,
    const float* __restrict__ bi_f, const float* __restrict__ bh_f,
    const float* __restrict__ bi_o, const float* __restrict__ bh_o,
    const float* __restrict__ bi_g, const float* __restrict__ bh_g,
    float* __restrict__ hz) {
  __shared__ float ws[8 * 1024];
  int g = blockIdx.x >> 7;
  int hb = blockIdx.x & 127;
  const float* wh = (g == 0) ? wh_i : (g == 1) ? wh_f : (g == 2) ? wh_o : wh_g;
  const float* bi = (g == 0) ? bi_i : (g == 1) ? bi_f : (g == 2) ? bi_o : bi_g;
  const float* bh = (g == 0) ? bh_i : (g == 1) ? bh_f : (g == 2) ? bh_o : bh_g;
  int tid = threadIdx.x;
  const float4* wsrc = reinterpret_cast<const float4*>(wh + hb * 8 * 1024);
  float4* wdst = reinterpret_cast<float4*>(ws);
  for (int i = tid; i < 2048; i += 256) wdst[i] = wsrc[i];
  __syncthreads();
  int b = tid & 31;
  int hh = tid >> 5;
  const float4* hv = reinterpret_cast<const float4*>(h0 + b * NH);
  const float4* wv = reinterpret_cast<const float4*>(ws + hh * NH);
  float acc = 0.f;
  for (int k = 0; k < 256; ++k) {
    float4 a = hv[k], w4 = wv[k];
    acc += a.x * w4.x + a.y * w4.y + a.z * w4.z + a.w * w4.w;
  }
  int h = hb * 8 + hh;
  hz[g * (32 * NH) + b * NH + h] = acc + bi[h] + bh[h];
}

__device__ __forceinline__ void load_lds16(const void* gsrc, void* lds) {
  __builtin_amdgcn_global_load_lds(
      (const __attribute__((address_space(1))) unsigned int*)gsrc,
      (__attribute__((address_space(3))) unsigned int*)lds, 16, 0, 0);
}

// 256x256 8-phase GEMM. BN=256 = 4 gates x 64 h. BK=64, 2 K-tiles/iter.
// Wave (wr,wc): M rows wr*128 + mi*16, N frags n = q*64 + wc*16 (q=0..3)
// -> per lane, acc[mi][q] holds gate q's z for one (m,h): thread-local epilogue.
__global__ __launch_bounds__(512, 2) void lstm_gemm8(
    const unsigned short* __restrict__ xb,   // [16384][1024] bf16
    const unsigned short* __restrict__ wb,   // [4][1024][1024] bf16 (i,f,o,g)
    const float* __restrict__ hz,            // [4][32][1024] f32
    const float* __restrict__ c0,            // [32][1024] f32
    float* __restrict__ out) {
  __shared__ unsigned short As[2][16384];    // [buf][256 rows][64 cols]
  __shared__ unsigned short Bs[2][16384];

  const int bid0 = blockIdx.x;                       // 1024 blocks
  const int bid = (bid0 & 7) * 128 + (bid0 >> 3);    // XCD swizzle (1024%8==0)
  const int ht = bid & 15;
  const int mt = bid >> 4;
  const int mBase = mt * 256;
  const int hBase = ht * 64;

  const int tid = threadIdx.x;
  const int lane = tid & 63;
  const int w = tid >> 6;
  const int wr = w >> 2;        // 0..1
  const int wc = w & 3;         // 0..3
  const int laneLow = lane & 15;
  const int lane4 = lane >> 4;  // 0..3
  const int lx = lane & 7;

  // staging geometry: per unit {A-half h | B-half h}, 2 rounds of 64 rows
  const int sRow = w * 8 + (lane >> 3);               // row within 64-row round
  const int sCol = ((lane & 7) ^ (lane >> 3)) * 8;    // inverse-swizzled col (elems)

#define STAGE_A(buf, kt, h)                                                        \
  do {                                                                             \
    int k0_ = (kt) * 64;                                                           \
    _Pragma("unroll") for (int r_ = 0; r_ < 2; ++r_) {                             \
      load_lds16(xb + (size_t)(mBase + (h) * 128 + r_ * 64 + sRow) * 1024 + k0_ + sCol, \
                 &As[buf][(h) * 8192 + r_ * 4096 + w * 512]);                      \
    }                                                                              \
  } while (0)

#define STAGE_B(buf, kt, h)                                                        \
  do {                                                                             \
    int k0_ = (kt) * 64;                                                           \
    _Pragma("unroll") for (int r_ = 0; r_ < 2; ++r_) {                             \
      load_lds16(wb + (size_t)((h) * 2 + r_) * 1048576 +                           \
                     (size_t)(hBase + sRow) * 1024 + k0_ + sCol,                   \
                 &Bs[buf][(h) * 8192 + r_ * 4096 + w * 512]);                      \
    }                                                                              \
  } while (0)

#define LDA(buf, mh)                                                               \
  do {                                                                             \
    _Pragma("unroll") for (int mi = 0; mi < 4; ++mi)                               \
    _Pragma("unroll") for (int kk = 0; kk < 2; ++kk) {                             \
      int row_ = wr * 128 + (mh) * 64 + mi * 16 + laneLow;                         \
      int slot_ = (kk * 4 + lane4) ^ lx;                                           \
      af[mi][kk] = *reinterpret_cast<const bf16x8*>(&As[buf][row_ * 64 + slot_ * 8]); \
    }                                                                              \
  } while (0)

#define LDB(buf, qh)                                                               \
  do {                                                                             \
    _Pragma("unroll") for (int q = 0; q < 2; ++q)                                  \
    _Pragma("unroll") for (int kk = 0; kk < 2; ++kk) {                             \
      int row_ = ((qh) * 2 + q) * 64 + wc * 16 + laneLow;                          \
      int slot_ = (kk * 4 + lane4) ^ lx;                                           \
      bq[q][kk] = *reinterpret_cast<const bf16x8*>(&Bs[buf][row_ * 64 + slot_ * 8]); \
    }                                                                              \
  } while (0)

#define DO_MFMA(MH, QH)                                                            \
  do {                                                                             \
    __builtin_amdgcn_s_setprio(1);                                                 \
    _Pragma("unroll") for (int mi = 0; mi < 4; ++mi)                               \
    _Pragma("unroll") for (int q = 0; q < 2; ++q)                                  \
    _Pragma("unroll") for (int kk = 0; kk < 2; ++kk)                               \
      acc[(MH) * 4 + mi][(QH) * 2 + q] = __builtin_amdgcn_mfma_f32_16x16x32_bf16(  \
          af[mi][kk], bq[q][kk], acc[(MH) * 4 + mi][(QH) * 2 + q], 0, 0, 0);       \
    __builtin_amdgcn_s_setprio(0);                                                 \
  } while (0)

#define BARRIER __builtin_amdgcn_s_barrier()
#define WAIT_LGKM0 asm volatile("s_waitcnt lgkmcnt(0)" ::: "memory")

  f32x4 acc[8][4];
#pragma unroll
  for (int i = 0; i < 8; ++i)
#pragma unroll
    for (int j = 0; j < 4; ++j) acc[i][j] = (f32x4){0.f, 0.f, 0.f, 0.f};

  // prologue: tile0 -> buf0 (all 4 units), tile1 B-half0 -> buf1
  STAGE_B(0, 0, 0); STAGE_B(0, 0, 1);
  STAGE_A(0, 0, 0); STAGE_A(0, 0, 1);
  STAGE_B(1, 1, 0);
  asm volatile("s_waitcnt vmcnt(2)" ::: "memory");
  BARRIER;

  bf16x8 af[4][2], bq[2][2];

  for (int it = 0; it < 8; ++it) {
    const int t1 = 2 * it + 1;
    const int t2 = (2 * it + 2 > 15) ? 15 : 2 * it + 2;
    const int t3 = (2 * it + 3 > 15) ? 15 : 2 * it + 3;

    // p0: buf0 (mh0,qh0); stage buf1: B-h1, A-h0 of t1
    LDA(0, 0); LDB(0, 0);
    STAGE_B(1, t1, 1); STAGE_A(1, t1, 0);
    BARRIER; WAIT_LGKM0; DO_MFMA(0, 0); BARRIER;

    // p1: (mh0,qh1); stage buf1: A-h1 of t1
    LDB(0, 1);
    STAGE_A(1, t1, 1);
    BARRIER; WAIT_LGKM0; DO_MFMA(0, 1); BARRIER;

    // p2: (mh1,qh0)
    LDA(0, 1); LDB(0, 0);
    BARRIER; WAIT_LGKM0; DO_MFMA(1, 0); BARRIER;

    // p3: (mh1,qh1); stage buf0: B-h0, A-h0 of t2; vmcnt(4) covers buf1=t1 done
    LDB(0, 1);
    STAGE_B(0, t2, 0); STAGE_A(0, t2, 0);
    asm volatile("s_waitcnt vmcnt(4)" ::: "memory");
    BARRIER; WAIT_LGKM0; DO_MFMA(1, 1); BARRIER;

    // p4: buf1 (mh0,qh0); stage buf0: B-h1 of t2
    LDA(1, 0); LDB(1, 0);
    STAGE_B(0, t2, 1);
    BARRIER; WAIT_LGKM0; DO_MFMA(0, 0); BARRIER;

    // p5: (mh0,qh1); stage buf0: A-h1 of t2
    LDB(1, 1);
    STAGE_A(0, t2, 1);
    BARRIER; WAIT_LGKM0; DO_MFMA(0, 1); BARRIER;

    // p6: (mh1,qh0)
    LDA(1, 1); LDB(1, 0);
    BARRIER; WAIT_LGKM0; DO_MFMA(1, 0); BARRIER;

    // p7: (mh1,qh1); stage buf1: B-h0 of t3; vmcnt(2) covers buf0=t2 done
    LDB(1, 1);
    STAGE_B(1, t3, 0);
    asm volatile("s_waitcnt vmcnt(2)" ::: "memory");
    BARRIER; WAIT_LGKM0; DO_MFMA(1, 1); BARRIER;
  }

  // epilogue: combine 4 gates (thread-local), activations, f32 writes
  const int b = mBase >> 9;  // uniform per block
  const int h = hBase + wc * 16 + laneLow;
  float hzv[4];
#pragma unroll
  for (int g = 0; g < 4; ++g) hzv[g] = hz[g * 32768 + b * NH + h];
  const float c0v = c0[b * NH + h];
#pragma unroll
  for (int mi16 = 0; mi16 < 8; ++mi16) {
#pragma unroll
    for (int r = 0; r < 4; ++r) {
      int m = mBase + wr * 128 + mi16 * 16 + lane4 * 4 + r;
      int t = m & 511;
      float zi = acc[mi16][0][r] + hzv[0];
      float zf = acc[mi16][1][r] + hzv[1];
      float zo = acc[mi16][2][r] + hzv[2];
      float zg = acc[mi16][3][r] + hzv[3];
      float iv = 1.f / (1.f + __expf(-zi));
      float fv = 1.f / (1.f + __expf(-zf));
      float ov = 1.f / (1.f + __expf(-zo));
      float gv = tanhf(zg);
      float cv = fv * c0v + iv * gv;
      float hval = ov * tanhf(cv);
      out[(size_t)t * 32768 + b * NH + h] = hval;
      if (t == 511) {
        out[HSEQ + b * NH + h] = hval;
        out[HSEQ + 32768 + b * NH + h] = cv;
      }
    }
  }
}

extern "C" void kernel_launch(void* const* d_in, const int* in_sizes, int n_in,
                              void* d_out, int out_size, void* d_ws, size_t ws_size,
                              hipStream_t stream) {
  const float* x    = (const float*)d_in[0];
  const float* h0   = (const float*)d_in[1];
  const float* c0   = (const float*)d_in[2];
  const float* w_ii = (const float*)d_in[3];
  const float* b_ii = (const float*)d_in[4];
  const float* w_hi = (const float*)d_in[5];
  const float* b_hi = (const float*)d_in[6];
  const float* w_if = (const float*)d_in[7];
  const float* b_if = (const float*)d_in[8];
  const float* w_hf = (const float*)d_in[9];
  const float* b_hf = (const float*)d_in[10];
  const float* w_io = (const float*)d_in[11];
  const float* b_io = (const float*)d_in[12];
  const float* w_ho = (const float*)d_in[13];
  const float* b_ho = (const float*)d_in[14];
  const float* w_ig = (const float*)d_in[15];
  const float* b_ig = (const float*)d_in[16];
  const float* w_hg = (const float*)d_in[17];
  const float* b_hg = (const float*)d_in[18];

  unsigned short* xb = (unsigned short*)d_ws;          // 16777216 bf16
  unsigned short* wb = xb + 16777216;                  // 4*1048576 bf16
  float* hz = (float*)(wb + 4 * 1048576);              // 4*32*1024 f32
  float* out = (float*)d_out;

  hipLaunchKernelGGL(cvt_all, dim3(3072), dim3(256), 0, stream,
                     x, w_ii, w_if, w_io, w_ig, xb, wb);
  hipLaunchKernelGGL(hz_kernel, dim3(512), dim3(256), 0, stream, h0,
                     w_hi, w_hf, w_ho, w_hg,
                     b_ii, b_hi, b_if, b_hf, b_io, b_ho, b_ig, b_hg, hz);
  hipLaunchKernelGGL(lstm_gemm8, dim3(1024), dim3(512), 0, stream, xb, wb, hz, c0, out);
}